// Round 3
// baseline (1552.987 us; speedup 1.0000x reference)
//
#include <hip/hip_runtime.h>

// Scaling-and-squaring integration of velocity fields.
// vel: [2, 160, 192, 160, 3] f32.  v0 = vel / 2^7;  7x: v = v + warp(v, v).
// Each step: dst[p] = src[p] + trilerp(src, p + src[p]) (coords clamped).
// Step 1 fuses the 2^-7 scale (power of two => bit-exact commute through lerp).
// Ping-pong: vel->out, out->ws, ws->out, ... ends in out. ws >= 117,964,800 B.
//
// R3 change: V=4 voxels per thread (w-consecutive). Round-2 counters showed
// latency-bound (VALU 27%, HBM 25%, occupancy 81%, FETCH near-ideal): the
// self-load -> gather dependent chain (~2 miss latencies/wave) dominates.
// 4 independent chains per wave => 4x memory-level parallelism; self-load and
// store become 48B-contiguous; index decompose amortized 4x.

#define DD 160
#define HH 192
#define WW 160
#define VOX (DD * HH * WW)      // 4,915,200 voxels per batch
#define NB 2
#define FIELD (VOX * 3)         // floats per batch
#define V 4                      // voxels per thread (w-consecutive; 160%4==0)

__device__ __forceinline__ void ld3(const float* __restrict__ p,
                                    float& a, float& b, float& c) {
    a = p[0]; b = p[1]; c = p[2];
}

__launch_bounds__(256)
__global__ void step_kernel(const float* __restrict__ src,
                            float* __restrict__ dst, float s) {
    int t = blockIdx.x * 256 + threadIdx.x;
    if (t >= NB * VOX / V) return;
    int idx0 = t * V;                     // first voxel id (global)
    int b  = idx0 / VOX;
    int r0 = idx0 - b * VOX;              // voxel within batch; 4-aligned in w
    int d  = r0 / (HH * WW);
    int r2 = r0 - d * (HH * WW);
    int h  = r2 / WW;
    int w0 = r2 - h * WW;                 // w0..w0+3 all in-row (160 % 4 == 0)

    const float* __restrict__ v = src + (size_t)b * FIELD;
    float* __restrict__ o       = dst + (size_t)b * FIELD;

    // ---- self velocities: 12 consecutive floats (coalesced, vectorizable)
    float sv[3 * V];
    #pragma unroll
    for (int i = 0; i < 3 * V; ++i) sv[i] = v[r0 * 3 + i];

    // ---- per-voxel addresses + weights
    int ro00[V], ro01[V], ro10[V], ro11[V], zo0[V], zo1[V];
    float wx[V], wy[V], wz[V];
    const float fd = (float)d, fh = (float)h;
    #pragma unroll
    for (int k = 0; k < V; ++k) {
        float x = fminf(fmaxf(fd + s * sv[3 * k + 0], 0.0f), (float)(DD - 1));
        float y = fminf(fmaxf(fh + s * sv[3 * k + 1], 0.0f), (float)(HH - 1));
        float z = fminf(fmaxf((float)(w0 + k) + s * sv[3 * k + 2], 0.0f),
                        (float)(WW - 1));
        float xf = floorf(x), yf = floorf(y), zf = floorf(z);
        int x0 = (int)xf, y0 = (int)yf, z0 = (int)zf;
        int x1 = min(x0 + 1, DD - 1);
        int y1 = min(y0 + 1, HH - 1);
        int z1 = min(z0 + 1, WW - 1);
        wx[k] = x - xf; wy[k] = y - yf; wz[k] = z - zf;
        ro00[k] = ((x0 * HH + y0) * WW) * 3;
        ro01[k] = ((x0 * HH + y1) * WW) * 3;
        ro10[k] = ((x1 * HH + y0) * WW) * 3;
        ro11[k] = ((x1 * HH + y1) * WW) * 3;
        zo0[k] = z0 * 3; zo1[k] = z1 * 3;
    }

    // ---- issue ALL 8*V corner gathers before any consumption (max MLP)
    float c[V][24];
    #pragma unroll
    for (int k = 0; k < V; ++k) {
        ld3(v + ro00[k] + zo0[k], c[k][0],  c[k][1],  c[k][2]);
        ld3(v + ro00[k] + zo1[k], c[k][3],  c[k][4],  c[k][5]);
        ld3(v + ro01[k] + zo0[k], c[k][6],  c[k][7],  c[k][8]);
        ld3(v + ro01[k] + zo1[k], c[k][9],  c[k][10], c[k][11]);
        ld3(v + ro10[k] + zo0[k], c[k][12], c[k][13], c[k][14]);
        ld3(v + ro10[k] + zo1[k], c[k][15], c[k][16], c[k][17]);
        ld3(v + ro11[k] + zo0[k], c[k][18], c[k][19], c[k][20]);
        ld3(v + ro11[k] + zo1[k], c[k][21], c[k][22], c[k][23]);
    }

    // ---- trilinear lerp + combine (same op order as reference)
    float out[3 * V];
    #pragma unroll
    for (int k = 0; k < V; ++k) {
        float iwx = 1.0f - wx[k], iwy = 1.0f - wy[k], iwz = 1.0f - wz[k];
        #pragma unroll
        for (int ch = 0; ch < 3; ++ch) {
            float c00 = c[k][0  + ch] * iwz + c[k][3  + ch] * wz[k];
            float c01 = c[k][6  + ch] * iwz + c[k][9  + ch] * wz[k];
            float c10 = c[k][12 + ch] * iwz + c[k][15 + ch] * wz[k];
            float c11 = c[k][18 + ch] * iwz + c[k][21 + ch] * wz[k];
            float c0 = c00 * iwy + c01 * wy[k];
            float c1 = c10 * iwy + c11 * wy[k];
            out[3 * k + ch] = s * (sv[3 * k + ch] + (c0 * iwx + c1 * wx[k]));
        }
    }

    // ---- store 12 consecutive floats (coalesced, vectorizable)
    #pragma unroll
    for (int i = 0; i < 3 * V; ++i) o[r0 * 3 + i] = out[i];
}

extern "C" void kernel_launch(void* const* d_in, const int* in_sizes, int n_in,
                              void* d_out, int out_size, void* d_ws, size_t ws_size,
                              hipStream_t stream) {
    const float* vel = (const float*)d_in[0];
    float* out = (float*)d_out;
    float* ws  = (float*)d_ws;   // needs >= 117,964,800 bytes

    const int nthreads = NB * VOX / V;           // 2,457,600
    const int blocks = (nthreads + 255) / 256;   // 9,600 exact

    // step 1 (fused 2^-7 scale), then 6 more; parity ends in d_out.
    step_kernel<<<blocks, 256, 0, stream>>>(vel, out, 1.0f / 128.0f);
    step_kernel<<<blocks, 256, 0, stream>>>(out, ws, 1.0f);
    step_kernel<<<blocks, 256, 0, stream>>>(ws, out, 1.0f);
    step_kernel<<<blocks, 256, 0, stream>>>(out, ws, 1.0f);
    step_kernel<<<blocks, 256, 0, stream>>>(ws, out, 1.0f);
    step_kernel<<<blocks, 256, 0, stream>>>(out, ws, 1.0f);
    step_kernel<<<blocks, 256, 0, stream>>>(ws, out, 1.0f);
}

// Round 4
// 822.308 us; speedup vs baseline: 1.8886x; 1.8886x over previous
//
#include <hip/hip_runtime.h>

// Scaling-and-squaring integration of velocity fields.
// vel: [2, 160, 192, 160, 3] f32.  v0 = vel / 2^7;  7x: v = v + warp(v, v).
// Each step: dst[p] = src[p] + trilerp(src, p + src[p]) (coords clamped).
// Step 1 fuses the 2^-7 scale (power of two => bit-exact commute through lerp).
// Ping-pong: vel->out, out->ws, ws->out, ... ends in out. ws >= 117,964,800 B.
//
// R4 change: V=4 chains per thread, BLOCK-STRIDE (voxel = blockStart + k*256
// + tid), NOT w-consecutive. R3's w-consecutive layout put lanes 48B apart in
// every instruction -> per-line utilization collapsed -> FETCH 3.4x field,
// WRITE +15% (partial-line RMW), 230us. Block-stride keeps lanes 12B apart
// per instruction (R2's exact coalescing: FETCH 1.13x, WRITE exact) while
// giving each thread 4 independent gather chains for memory-level parallelism
// (R2 was latency-bound: VALU 27%, HBM 25%, occ 81% -- nothing saturated).

#define DD 160
#define HH 192
#define WW 160
#define VOX (DD * HH * WW)      // 4,915,200 voxels per batch
#define NB 2
#define FIELD (VOX * 3)         // floats per batch
#define V 4                      // chains per thread, stride 256 voxels
#define BLK 256

__device__ __forceinline__ void ld3(const float* __restrict__ p,
                                    float& a, float& b, float& c) {
    a = p[0]; b = p[1]; c = p[2];
}

__launch_bounds__(BLK)
__global__ void step_kernel(const float* __restrict__ src,
                            float* __restrict__ dst, float s) {
    const int start = blockIdx.x * (BLK * V) + threadIdx.x;

    // ---- phase 1: per-chain self-load (coalesced: lanes 12B apart)
    size_t fbase[V];             // batch offset in floats
    int    r[V];                 // voxel within batch
    float  sv[V][3];
    #pragma unroll
    for (int k = 0; k < V; ++k) {
        int idx = start + k * BLK;
        int b = idx / VOX;
        r[k] = idx - b * VOX;
        fbase[k] = (size_t)b * FIELD;
        const float* __restrict__ v = src + fbase[k];
        ld3(v + r[k] * 3, sv[k][0], sv[k][1], sv[k][2]);
    }

    // ---- phase 2: addresses + weights per chain
    int ro00[V], ro01[V], ro10[V], ro11[V], zo0[V], zo1[V];
    float wx[V], wy[V], wz[V];
    #pragma unroll
    for (int k = 0; k < V; ++k) {
        int d  = r[k] / (HH * WW);
        int r2 = r[k] - d * (HH * WW);
        int h  = r2 / WW;
        int w  = r2 - h * WW;
        float x = fminf(fmaxf((float)d + s * sv[k][0], 0.0f), (float)(DD - 1));
        float y = fminf(fmaxf((float)h + s * sv[k][1], 0.0f), (float)(HH - 1));
        float z = fminf(fmaxf((float)w + s * sv[k][2], 0.0f), (float)(WW - 1));
        float xf = floorf(x), yf = floorf(y), zf = floorf(z);
        int x0 = (int)xf, y0 = (int)yf, z0 = (int)zf;
        int x1 = min(x0 + 1, DD - 1);
        int y1 = min(y0 + 1, HH - 1);
        int z1 = min(z0 + 1, WW - 1);
        wx[k] = x - xf; wy[k] = y - yf; wz[k] = z - zf;
        ro00[k] = ((x0 * HH + y0) * WW) * 3;
        ro01[k] = ((x0 * HH + y1) * WW) * 3;
        ro10[k] = ((x1 * HH + y0) * WW) * 3;
        ro11[k] = ((x1 * HH + y1) * WW) * 3;
        zo0[k] = z0 * 3; zo1[k] = z1 * 3;
    }

    // ---- phase 3: gathers (independent across chains -> MLP), then lerp
    float out[V][3];
    #pragma unroll
    for (int k = 0; k < V; ++k) {
        const float* __restrict__ v = src + fbase[k];
        float a000, b000, c000, a001, b001, c001;
        float a010, b010, c010, a011, b011, c011;
        float a100, b100, c100, a101, b101, c101;
        float a110, b110, c110, a111, b111, c111;
        ld3(v + ro00[k] + zo0[k], a000, b000, c000);
        ld3(v + ro00[k] + zo1[k], a001, b001, c001);
        ld3(v + ro01[k] + zo0[k], a010, b010, c010);
        ld3(v + ro01[k] + zo1[k], a011, b011, c011);
        ld3(v + ro10[k] + zo0[k], a100, b100, c100);
        ld3(v + ro10[k] + zo1[k], a101, b101, c101);
        ld3(v + ro11[k] + zo0[k], a110, b110, c110);
        ld3(v + ro11[k] + zo1[k], a111, b111, c111);

        float iwx = 1.0f - wx[k], iwy = 1.0f - wy[k], iwz = 1.0f - wz[k];
        {
            float c00 = a000 * iwz + a001 * wz[k];
            float c01 = a010 * iwz + a011 * wz[k];
            float c10 = a100 * iwz + a101 * wz[k];
            float c11 = a110 * iwz + a111 * wz[k];
            float c0 = c00 * iwy + c01 * wy[k];
            float c1 = c10 * iwy + c11 * wy[k];
            out[k][0] = s * (sv[k][0] + (c0 * iwx + c1 * wx[k]));
        }
        {
            float c00 = b000 * iwz + b001 * wz[k];
            float c01 = b010 * iwz + b011 * wz[k];
            float c10 = b100 * iwz + b101 * wz[k];
            float c11 = b110 * iwz + b111 * wz[k];
            float c0 = c00 * iwy + c01 * wy[k];
            float c1 = c10 * iwy + c11 * wy[k];
            out[k][1] = s * (sv[k][1] + (c0 * iwx + c1 * wx[k]));
        }
        {
            float c00 = c000 * iwz + c001 * wz[k];
            float c01 = c010 * iwz + c011 * wz[k];
            float c10 = c100 * iwz + c101 * wz[k];
            float c11 = c110 * iwz + c111 * wz[k];
            float c0 = c00 * iwy + c01 * wy[k];
            float c1 = c10 * iwy + c11 * wy[k];
            out[k][2] = s * (sv[k][2] + (c0 * iwx + c1 * wx[k]));
        }
    }

    // ---- phase 4: stores (coalesced: lanes 12B apart, full lines per wave)
    #pragma unroll
    for (int k = 0; k < V; ++k) {
        float* __restrict__ o = dst + fbase[k] + (size_t)r[k] * 3;
        o[0] = out[k][0]; o[1] = out[k][1]; o[2] = out[k][2];
    }
}

extern "C" void kernel_launch(void* const* d_in, const int* in_sizes, int n_in,
                              void* d_out, int out_size, void* d_ws, size_t ws_size,
                              hipStream_t stream) {
    const float* vel = (const float*)d_in[0];
    float* out = (float*)d_out;
    float* ws  = (float*)d_ws;   // needs >= 117,964,800 bytes

    const int nthreads = NB * VOX / V;             // 2,457,600
    const int blocks = (nthreads + BLK - 1) / BLK; // 9,600 exact

    // step 1 (fused 2^-7 scale), then 6 more; parity ends in d_out.
    step_kernel<<<blocks, BLK, 0, stream>>>(vel, out, 1.0f / 128.0f);
    step_kernel<<<blocks, BLK, 0, stream>>>(out, ws, 1.0f);
    step_kernel<<<blocks, BLK, 0, stream>>>(ws, out, 1.0f);
    step_kernel<<<blocks, BLK, 0, stream>>>(out, ws, 1.0f);
    step_kernel<<<blocks, BLK, 0, stream>>>(ws, out, 1.0f);
    step_kernel<<<blocks, BLK, 0, stream>>>(out, ws, 1.0f);
    step_kernel<<<blocks, BLK, 0, stream>>>(ws, out, 1.0f);
}

// Round 7
// 755.948 us; speedup vs baseline: 2.0544x; 1.0878x over previous
//
#include <hip/hip_runtime.h>

// Scaling-and-squaring integration of velocity fields.
// vel: [2, 160, 192, 160, 3] f32.  v0 = vel / 2^7;  7x: v = v + warp(v, v).
// Each step: dst[p] = src[p] + trilerp(src, p + src[p]) (coords clamped).
// Step 1 fuses the 2^-7 scale (power of two => bit-exact commute through lerp).
// Ping-pong: vel->out, out->ws, ws->out, ... ends in out. ws >= 117,964,800 B.
//
// R5 change: cut VMEM instruction count 30 -> 12 per voxel. R2/R4 both landed
// at ~124/137us with identical 30-dword-instr/voxel despite different ILP and
// occupancy => bound by vector-memory address throughput (~16cy per wave64
// VMEM instr => 600 waves/CU * 30 * 16cy = 120us, matches). Width is ~free:
// fuse each (x,y) corner row's z0/z1 pair (6 contiguous floats, 24B) into
// dwordx4+dwordx2; self and store as x2+x1. z-edge (z0==W-1): base at
// min(z0,W-2), branchless 3-float window select (wz==0 there, exact).

#define DD 160
#define HH 192
#define WW 160
#define VOX (DD * HH * WW)      // 4,915,200 voxels per batch
#define NB 2
#define FIELD (VOX * 3)         // floats per batch

struct __attribute__((packed, aligned(4))) pf4 { float x, y, z, w; };
struct __attribute__((packed, aligned(4))) pf2 { float x, y; };

__launch_bounds__(256)
__global__ void step_kernel(const float* __restrict__ src,
                            float* __restrict__ dst, float s) {
    int idx = blockIdx.x * 256 + threadIdx.x;   // voxel id over both batches
    if (idx >= NB * VOX) return;
    int b  = idx / VOX;
    int r  = idx - b * VOX;                     // voxel within batch
    int d  = r / (HH * WW);
    int r2 = r - d * (HH * WW);
    int h  = r2 / WW;
    int w  = r2 - h * WW;

    const float* __restrict__ v = src + (size_t)b * FIELD;
    float* __restrict__ o       = dst + (size_t)b * FIELD;

    // ---- self velocity: 12B as x2 + x1 (2 VMEM instrs)
    pf2 sl = *(const pf2*)(v + r * 3);
    float rv0 = sl.x, rv1 = sl.y;
    float rv2 = v[r * 3 + 2];

    // sample location = grid + s*v, clamped to [0, dim-1]
    float x = fminf(fmaxf((float)d + s * rv0, 0.0f), (float)(DD - 1));
    float y = fminf(fmaxf((float)h + s * rv1, 0.0f), (float)(HH - 1));
    float z = fminf(fmaxf((float)w + s * rv2, 0.0f), (float)(WW - 1));

    float xf = floorf(x), yf = floorf(y), zf = floorf(z);
    int x0 = (int)xf, y0 = (int)yf, z0 = (int)zf;
    int x1 = min(x0 + 1, DD - 1);
    int y1 = min(y0 + 1, HH - 1);
    float wx = x - xf, wy = y - yf, wz = z - zf;
    float iwx = 1.0f - wx, iwy = 1.0f - wy, iwz = 1.0f - wz;

    // z window: 6 contiguous floats starting at zb (zb<=W-2 so no row overrun)
    int zb = min(z0, WW - 2);
    bool sel = (z0 > zb);        // true iff z0 == W-1 (then wz == 0 exactly)

    int ro00 = ((x0 * HH + y0) * WW + zb) * 3;
    int ro01 = ((x0 * HH + y1) * WW + zb) * 3;
    int ro10 = ((x1 * HH + y0) * WW + zb) * 3;
    int ro11 = ((x1 * HH + y1) * WW + zb) * 3;

    // ---- 4 corner-row loads: dwordx4 + dwordx2 each (8 VMEM instrs)
    pf4 a00 = *(const pf4*)(v + ro00); pf2 b00 = *(const pf2*)(v + ro00 + 4);
    pf4 a01 = *(const pf4*)(v + ro01); pf2 b01 = *(const pf2*)(v + ro01 + 4);
    pf4 a10 = *(const pf4*)(v + ro10); pf2 b10 = *(const pf2*)(v + ro10 + 4);
    pf4 a11 = *(const pf4*)(v + ro11); pf2 b11 = *(const pf2*)(v + ro11 + 4);

    // f[0..5] per row = {a.x a.y a.z a.w b.x b.y}; cz0 = sel?f[3..5]:f[0..2];
    // cz1 = f[3..5] (when sel, wz==0 so cz1 is weighted out; value==cz0 anyway)
    float g000 = sel ? a00.w : a00.x, g001 = sel ? b00.x : a00.y, g002 = sel ? b00.y : a00.z;
    float g010 = sel ? a01.w : a01.x, g011 = sel ? b01.x : a01.y, g012 = sel ? b01.y : a01.z;
    float g100 = sel ? a10.w : a10.x, g101 = sel ? b10.x : a10.y, g102 = sel ? b10.y : a10.z;
    float g110 = sel ? a11.w : a11.x, g111 = sel ? b11.x : a11.y, g112 = sel ? b11.y : a11.z;

    float out0, out1, out2;
    {   // channel 0
        float c00 = g000 * iwz + a00.w * wz;
        float c01 = g010 * iwz + a01.w * wz;
        float c10 = g100 * iwz + a10.w * wz;
        float c11 = g110 * iwz + a11.w * wz;
        float c0 = c00 * iwy + c01 * wy;
        float c1 = c10 * iwy + c11 * wy;
        out0 = s * (rv0 + (c0 * iwx + c1 * wx));
    }
    {   // channel 1
        float c00 = g001 * iwz + b00.x * wz;
        float c01 = g011 * iwz + b01.x * wz;
        float c10 = g101 * iwz + b10.x * wz;
        float c11 = g111 * iwz + b11.x * wz;
        float c0 = c00 * iwy + c01 * wy;
        float c1 = c10 * iwy + c11 * wy;
        out1 = s * (rv1 + (c0 * iwx + c1 * wx));
    }
    {   // channel 2
        float c00 = g002 * iwz + b00.y * wz;
        float c01 = g012 * iwz + b01.y * wz;
        float c10 = g102 * iwz + b10.y * wz;
        float c11 = g112 * iwz + b11.y * wz;
        float c0 = c00 * iwy + c01 * wy;
        float c1 = c10 * iwy + c11 * wy;
        out2 = s * (rv2 + (c0 * iwx + c1 * wx));
    }

    // ---- store 12B as x2 + x1 (2 VMEM instrs)
    pf2 st; st.x = out0; st.y = out1;
    *(pf2*)(o + r * 3) = st;
    o[r * 3 + 2] = out2;
}

extern "C" void kernel_launch(void* const* d_in, const int* in_sizes, int n_in,
                              void* d_out, int out_size, void* d_ws, size_t ws_size,
                              hipStream_t stream) {
    const float* vel = (const float*)d_in[0];
    float* out = (float*)d_out;
    float* ws  = (float*)d_ws;   // needs >= 117,964,800 bytes

    const int nthreads = NB * VOX;                 // 9,830,400
    const int blocks = (nthreads + 255) / 256;     // 38,400 exact

    // step 1 (fused 2^-7 scale), then 6 more; parity ends in d_out.
    step_kernel<<<blocks, 256, 0, stream>>>(vel, out, 1.0f / 128.0f);
    step_kernel<<<blocks, 256, 0, stream>>>(out, ws, 1.0f);
    step_kernel<<<blocks, 256, 0, stream>>>(ws, out, 1.0f);
    step_kernel<<<blocks, 256, 0, stream>>>(out, ws, 1.0f);
    step_kernel<<<blocks, 256, 0, stream>>>(ws, out, 1.0f);
    step_kernel<<<blocks, 256, 0, stream>>>(out, ws, 1.0f);
    step_kernel<<<blocks, 256, 0, stream>>>(ws, out, 1.0f);
}